// Round 13
// baseline (455.973 us; speedup 1.0000x reference)
//
#include <hip/hip_runtime.h>

#define NB 256            // blocks (1 per CU — cooperative co-residency proven)
#define BT 1024           // threads per block (16 waves; launch-proven in r5)
#define MSTEPS 8
// Fixed problem shape: L = 500000.
#define CHUNK 1954        // ceil(500000 / NB) rows per block
#define LDSR 1024         // rows resident in LDS (dense 128 B rows, 131 KB — launch-safe margin)

typedef float v4f __attribute__((ext_vector_type(4)));

// Workspace layout (r9-proven footprint):
//  u32 region (memset to 0 at launch, 5120 B): per-iter counter block, stride 160 u32:
//    [iter*160 + g*16]  g<8 : sub-arrival counter for block-group g = b>>5
//    [iter*160 + 128]        : super-arrival counter (8 groups)
//    [iter*160 + 144]        : release flag
//  float region:
//    ws[4096 + iter*132*NB + c*NB + b] : per-iteration partial tables — FRESH each iter.
//  Coherence contract (r8-r11 evidence): publish = system-scope store + per-wave
//  vmcnt(0) drain before arrival; consume = PLAIN loads on lines never cached
//  earlier in the launch (fresh per-iter buffers only).

struct PParams {
  const float* candidate;
  const float* z_past;
  const float* q_w; const float* q_b;
  const float* k_w; const float* k_b;
  const float* v_w; const float* v_b;
  const float* o_w; const float* o_b;
  const float* rel_bias;
  const float* coupling;
  const float* norm_scale;
  float* out;
  float* ws;
  int L;
};

__device__ __forceinline__ float mish_f(float x) {
  float sp = fmaxf(x, 0.0f) + log1pf(expf(-fabsf(x)));
  return x * tanhf(sp);
}

// Recompute q projection, folded score vectors a_h (pre-scaled by inv_sqrt_d=0.5),
// and the l<64 relative-bias delta table, from the current state sZ.
// Must be called by ALL threads of the block (contains barriers).
__device__ void compute_qar(const PParams& p, int tid,
                            float* sZ, float* sQ, float* sA, float* sRel) {
  if (tid < 32) {
    float acc = p.q_b[tid];
    const float* row = p.q_w + tid * 32;
    #pragma unroll
    for (int c = 0; c < 32; ++c) acc = fmaf(row[c], sZ[c], acc);
    sQ[tid] = acc;
  }
  __syncthreads();
  if (tid < 128) {
    int h = tid >> 5, c = tid & 31;
    float acc = 0.f;
    #pragma unroll
    for (int jj = 0; jj < 8; ++jj)
      acc = fmaf(sQ[8 * h + jj], p.k_w[(8 * h + jj) * 32 + c], acc);
    sA[tid] = 0.5f * acc;               // fold inv_sqrt_d
  }
  if (tid >= 256 && tid < 512) {       // BT=1024: bound rel-bias writers to 256 lanes
    // rel-bias delta vs the saturated idx=128 entry (constant part cancels in softmax)
    int t = tid - 256;
    int l = t >> 2, h = t & 3;
    float acc = 0.f;
    #pragma unroll
    for (int jj = 0; jj < 8; ++jj) {
      int jidx = 8 * h + jj;
      acc = fmaf(sQ[jidx],
                 p.rel_bias[(l + 64) * 32 + jidx] - p.rel_bias[128 * 32 + jidx],
                 acc);
    }
    sRel[t] = 0.5f * acc;
  }
  __syncthreads();
}

// One l-row contribution (octet scheme: 8 lanes own one 32-float row, 4 floats each).
// Numerically validated in r5 (absmax 0.0).
__device__ __forceinline__ void trip_body(const v4f (&A)[4], v4f zv,
                                          const float* sRel, bool dorel, int relrow,
                                          v4f (&S)[4], v4f& Zc) {
  float d0 = 0.f, d1 = 0.f, d2 = 0.f, d3 = 0.f;
  #pragma unroll
  for (int k = 0; k < 4; ++k) {
    d0 = fmaf(A[0][k], zv[k], d0);
    d1 = fmaf(A[1][k], zv[k], d1);
    d2 = fmaf(A[2][k], zv[k], d2);
    d3 = fmaf(A[3][k], zv[k], d3);
  }
  // complete the 32-wide dot across the 8-lane octet
  d0 += __shfl_xor(d0, 1); d0 += __shfl_xor(d0, 2); d0 += __shfl_xor(d0, 4);
  d1 += __shfl_xor(d1, 1); d1 += __shfl_xor(d1, 2); d1 += __shfl_xor(d1, 4);
  d2 += __shfl_xor(d2, 1); d2 += __shfl_xor(d2, 2); d2 += __shfl_xor(d2, 4);
  d3 += __shfl_xor(d3, 1); d3 += __shfl_xor(d3, 2); d3 += __shfl_xor(d3, 4);
  if (dorel) {
    const float4 r = reinterpret_cast<const float4*>(sRel)[relrow];
    d0 += r.x; d1 += r.y; d2 += r.z; d3 += r.w;
  }
  float w0 = __expf(d0), w1 = __expf(d1), w2 = __expf(d2), w3 = __expf(d3);
  Zc[0] += w0; Zc[1] += w1; Zc[2] += w2; Zc[3] += w3;
  S[0] += zv * w0;
  S[1] += zv * w1;
  S[2] += zv * w2;
  S[3] += zv * w3;
}

__global__ __launch_bounds__(BT)
void photonic_kernel(PParams p) {
  __shared__ float sZ[32];
  __shared__ float sQ[32];
  __shared__ float sOutV[32];
  __shared__ float sZn[32];
  __shared__ __align__(16) float sA[128];     // a[h][c]
  __shared__ __align__(16) float sRel[256];   // relT[l][h], l<64
  __shared__ float sRed[BT / 64][8][20];      // per-wave reduced (S[4][4] + Z[4]) per octet-slot
  __shared__ float sP[132][4];                // level-2 strip sums
  __shared__ float sSS[128];                  // global-reduced S[h][c]
  __shared__ float sSZ[4];                    // global-reduced Z[h]
  __shared__ __align__(16) float sZp[LDSR * 32];  // LDS-resident z rows (dense 128 B)

  const int tid  = threadIdx.x;
  const int b    = blockIdx.x;
  const int o    = tid & 7;        // lane-slot within octet (owns cols [4o, 4o+4))
  const int oct  = tid >> 3;       // octet index 0..127
  const int wave = tid >> 6;       // 0..15
  const int lane = tid & 63;

  const int chunk0 = b * CHUNK;
  const int clen   = min(CHUNK, p.L - chunk0);   // 1954, last block 1730
  const int ldsl   = min(clen, (int)LDSR);       // 1024 everywhere

  // init state z = candidate (real-interleaved flat 32)
  if (tid < 32) sZ[tid] = p.candidate[tid];
  __syncthreads();
  compute_qar(p, tid, sZ, sQ, sA, sRel);

  for (int iter = 0; iter < MSTEPS; ++iter) {
    // stage my 4-column slice of a[h][*] into registers
    v4f A[4];
    #pragma unroll
    for (int h = 0; h < 4; ++h)
      A[h] = *reinterpret_cast<const v4f*>(sA + h * 32 + o * 4);

    v4f S[4];
    #pragma unroll
    for (int h = 0; h < 4; ++h) S[h] = 0.f;
    v4f Zc = 0.f;

    if (iter == 0) {
      // ---- first pass: LDS rows come from HBM and are stashed; rest streamed ----
      #pragma unroll
      for (int t = 0; t < 8; ++t) {
        int li = oct + (t << 7);    // LDSR = 1024 = 8*128: no bounds check needed
        v4f zv = *reinterpret_cast<const v4f*>(
            p.z_past + (size_t)(chunk0 + li) * 32 + o * 4);
        *reinterpret_cast<v4f*>(sZp + li * 32 + o * 4) = zv;
        trip_body(A, zv, sRel, (b == 0) && (t == 0) && (oct < 64), oct, S, Zc);
      }
    } else {
      // ---- steady state: LDS-resident rows ----
      #pragma unroll
      for (int t = 0; t < 8; ++t) {
        int li = oct + (t << 7);
        v4f zv = *reinterpret_cast<const v4f*>(sZp + li * 32 + o * 4);
        trip_body(A, zv, sRel, (b == 0) && (t == 0) && (oct < 64), oct, S, Zc);
      }
    }
    // ---- streamed remainder (~30 MB grid-wide; L2/L3-resident after pass 1) ----
    for (int r = LDSR + oct; r < clen; r += 128) {
      v4f zv = *reinterpret_cast<const v4f*>(
          p.z_past + (size_t)(chunk0 + r) * 32 + o * 4);
      trip_body(A, zv, sRel, false, 0, S, Zc);
    }

    // reduce across the 8 octets of each wave (lane&7 == o is preserved)
    #pragma unroll
    for (int m = 8; m <= 32; m <<= 1) {
      #pragma unroll
      for (int h = 0; h < 4; ++h) {
        #pragma unroll
        for (int k = 0; k < 4; ++k) S[h][k] += __shfl_xor(S[h][k], m);
        Zc[h] += __shfl_xor(Zc[h], m);
      }
    }
    if (lane < 8) {  // lanes 0..7: lane == o
      #pragma unroll
      for (int h = 0; h < 4; ++h) {
        #pragma unroll
        for (int k = 0; k < 4; ++k) sRed[wave][lane][h * 4 + k] = S[h][k];
        sRed[wave][lane][16 + h] = Zc[h];
      }
    }
    __syncthreads();

    // ---- publish per-block partials, system-scope (performed at IF);
    //      FRESH buffer per iteration (coherence contract) ----
    float* pb = p.ws + 4096 + iter * (132 * NB);
    if (tid < 132) {
      float acc = 0.f;
      if (tid < 128) {
        int h = tid >> 5, c = tid & 31;
        int jj = c >> 2, k = c & 3;
        #pragma unroll
        for (int w2 = 0; w2 < BT / 64; ++w2) acc += sRed[w2][jj][h * 4 + k];
      } else {
        int h = tid - 128;
        #pragma unroll
        for (int w2 = 0; w2 < BT / 64; ++w2) acc += sRed[w2][0][16 + h];
      }
      __hip_atomic_store(&pb[tid * NB + b], acc, __ATOMIC_RELAXED,
                         __HIP_MEMORY_SCOPE_SYSTEM);
    }
    // every wave drains its own stores; the barrier then guarantees all 132
    // stores of this block are performed before tid 0 arrives.
    asm volatile("s_waitcnt vmcnt(0)" ::: "memory");
    __syncthreads();

    // ---- two-level arrival + flag barrier (r9-proven), system scope ----
    {
      unsigned* cb = reinterpret_cast<unsigned*>(p.ws) + iter * 160;
      if (tid == 0) {
        unsigned* sub = cb + ((b >> 5) << 4);   // 8 counters on separate lines
        if (__hip_atomic_fetch_add(sub, 1u, __ATOMIC_RELAXED,
                                   __HIP_MEMORY_SCOPE_SYSTEM) == 31u) {
          if (__hip_atomic_fetch_add(cb + 128, 1u, __ATOMIC_RELAXED,
                                     __HIP_MEMORY_SCOPE_SYSTEM) == 7u) {
            __hip_atomic_store(cb + 144, 1u, __ATOMIC_RELAXED,
                               __HIP_MEMORY_SCOPE_SYSTEM);
          }
        }
        while (__hip_atomic_load(cb + 144, __ATOMIC_RELAXED,
                                 __HIP_MEMORY_SCOPE_SYSTEM) == 0u)
          __builtin_amdgcn_s_sleep(1);
      }
      __syncthreads();
    }

    // ---- level-2 reduce with plain coalesced float4 loads (fresh per-iter
    //      buffer: no cache can hold a stale copy). First 512 threads. ----
    if (tid < 512) {
      const int cc = tid >> 2;       // component 0..127
      const int qq = tid & 3;        // quarter-strip of the 256-wide row
      const float4* pp =
          reinterpret_cast<const float4*>(pb + cc * NB) + qq * (NB / 16);
      float acc = 0.f;
      #pragma unroll
      for (int i = 0; i < NB / 16; ++i) {
        float4 v4 = pp[i];
        acc += (v4.x + v4.y) + (v4.z + v4.w);
      }
      sP[cc][qq] = acc;
      if (tid < 16) {                // components 128..131 (the Z row)
        const int cc2 = 128 + (tid >> 2);
        const float4* pp2 =
            reinterpret_cast<const float4*>(pb + cc2 * NB) + qq * (NB / 16);
        float acc2 = 0.f;
        #pragma unroll
        for (int i = 0; i < NB / 16; ++i) {
          float4 v4 = pp2[i];
          acc2 += (v4.x + v4.y) + (v4.z + v4.w);
        }
        sP[cc2][qq] = acc2;
      }
    }
    __syncthreads();
    if (tid < 132) {
      float acc = sP[tid][0] + sP[tid][1] + sP[tid][2] + sP[tid][3];
      if (tid < 128) sSS[tid] = acc; else sSZ[tid - 128] = acc;
    }
    __syncthreads();

    // out_flat[j'] = v_w[j',:] @ (S_h / Z_h) + v_b[j']   (h = j'>>3)
    if (tid < 32) {
      int h = tid >> 3;
      float acc = 0.f;
      const float* row = p.v_w + tid * 32;
      #pragma unroll
      for (int c = 0; c < 32; ++c) acc = fmaf(row[c], sSS[h * 32 + c], acc);
      sOutV[tid] = acc / sSZ[h] + p.v_b[tid];
    }
    __syncthreads();
    // mod = o_w @ out + o_b ; z += coupling*mod ; mish
    if (tid < 32) {
      float acc = p.o_b[tid];
      const float* row = p.o_w + tid * 32;
      #pragma unroll
      for (int c = 0; c < 32; ++c) acc = fmaf(row[c], sOutV[c], acc);
      float zv2 = sZ[tid] + p.coupling[0] * acc;
      sZn[tid] = mish_f(zv2);
    }
    __syncthreads();
    // layer-norm over the 16 real / 16 imag components separately
    if (tid < 32) {
      int par = tid & 1;
      float m = 0.f;
      #pragma unroll
      for (int e = 0; e < 16; ++e) m += sZn[2 * e + par];
      m *= (1.f / 16.f);
      float v = 0.f;
      #pragma unroll
      for (int e = 0; e < 16; ++e) { float dd = sZn[2 * e + par] - m; v = fmaf(dd, dd, v); }
      v *= (1.f / 16.f);
      sZ[tid] = (sZn[tid] - m) * rsqrtf(v + 1e-5f) * p.norm_scale[0];
    }
    __syncthreads();

    if (iter != MSTEPS - 1) {
      compute_qar(p, tid, sZ, sQ, sA, sRel);
    } else {
      if (b == 0 && tid < 32) p.out[tid] = sZ[tid];
    }
  }
}

extern "C" void kernel_launch(void* const* d_in, const int* in_sizes, int n_in,
                              void* d_out, int out_size, void* d_ws, size_t ws_size,
                              hipStream_t stream) {
  PParams p;
  p.candidate  = (const float*)d_in[0];
  p.z_past     = (const float*)d_in[1];
  p.q_w = (const float*)d_in[2];  p.q_b = (const float*)d_in[3];
  p.k_w = (const float*)d_in[4];  p.k_b = (const float*)d_in[5];
  p.v_w = (const float*)d_in[6];  p.v_b = (const float*)d_in[7];
  p.o_w = (const float*)d_in[8];  p.o_b = (const float*)d_in[9];
  p.rel_bias   = (const float*)d_in[10];
  p.coupling   = (const float*)d_in[11];
  p.norm_scale = (const float*)d_in[12];
  p.out = (float*)d_out;
  p.ws  = (float*)d_ws;
  p.L   = in_sizes[1] / 32;

  // zero the per-iteration barrier counters (8 iters x 160 u32 = 5120 B);
  // captured as a graph node -> re-zeroed every replay. Partial tables are
  // fully written before being read each iteration.
  hipMemsetAsync(d_ws, 0, 5120, stream);

  void* args[] = { &p };
  hipLaunchCooperativeKernel((const void*)photonic_kernel,
                             dim3(NB), dim3(BT), args, 0, stream);
}

// Round 15
// 355.510 us; speedup vs baseline: 1.2826x; 1.2826x over previous
//
#include <hip/hip_runtime.h>

#define NBA 512           // blocks in the accumulate kernel (no co-residency requirement)
#define BTA 512           // threads per block (8 waves, quad scheme)
#define MSTEPS 8
#define CHUNK 977         // ceil(500000 / NBA) rows per block

typedef float v8f __attribute__((ext_vector_type(8)));
typedef float v4f __attribute__((ext_vector_type(4)));

// ws layout (floats):
//   [k*64 + i], k<9      : z slot at start of iter k (slot 0 unused; A reads candidate at iter 0)
//   [1024 + c*NBA + b]   : partial table, component-major (reused across iters —
//                          SAFE: kernel boundaries provide release/acquire coherence)

struct PParams {
  const float* candidate;
  const float* z_past;
  const float* q_w; const float* q_b;
  const float* k_w; const float* k_b;
  const float* v_w; const float* v_b;
  const float* o_w; const float* o_b;
  const float* rel_bias;
  const float* coupling;
  const float* norm_scale;
  float* out;
  float* ws;
  int L;
};

__device__ __forceinline__ float mish_f(float x) {
  float sp = fmaxf(x, 0.0f) + log1pf(expf(-fabsf(x)));
  return x * tanhf(sp);
}

// Recompute q projection, folded score vectors a_h (pre-scaled by inv_sqrt_d=0.5),
// and the l<64 relative-bias delta table, from the current state sZ.
// Must be called by ALL threads of the block (contains barriers).
__device__ void compute_qar(const PParams& p, int tid,
                            float* sZ, float* sQ, float* sA, float* sRel) {
  if (tid < 32) {
    float acc = p.q_b[tid];
    const float* row = p.q_w + tid * 32;
    #pragma unroll
    for (int c = 0; c < 32; ++c) acc = fmaf(row[c], sZ[c], acc);
    sQ[tid] = acc;
  }
  __syncthreads();
  if (tid < 128) {
    int h = tid >> 5, c = tid & 31;
    float acc = 0.f;
    #pragma unroll
    for (int jj = 0; jj < 8; ++jj)
      acc = fmaf(sQ[8 * h + jj], p.k_w[(8 * h + jj) * 32 + c], acc);
    sA[tid] = 0.5f * acc;               // fold inv_sqrt_d
  }
  if (tid >= 256) {
    // rel-bias delta vs the saturated idx=128 entry (constant part cancels in softmax)
    int t = tid - 256;
    int l = t >> 2, h = t & 3;
    float acc = 0.f;
    #pragma unroll
    for (int jj = 0; jj < 8; ++jj) {
      int jidx = 8 * h + jj;
      acc = fmaf(sQ[jidx],
                 p.rel_bias[(l + 64) * 32 + jidx] - p.rel_bias[128 * 32 + jidx],
                 acc);
    }
    sRel[t] = 0.5f * acc;
  }
  __syncthreads();
}

// One l-row contribution (quad scheme: 4 lanes own one 32-float row, 8 floats each).
// Numerics proven in r0/r9 (absmax 0.0).
__device__ __forceinline__ void trip_body(const v8f (&A)[4], v8f zv,
                                          const float* sRel, bool dorel, int relrow,
                                          v8f (&S)[4], v4f& Zc) {
  float d0 = 0.f, d1 = 0.f, d2 = 0.f, d3 = 0.f;
  #pragma unroll
  for (int k = 0; k < 8; ++k) {
    d0 = fmaf(A[0][k], zv[k], d0);
    d1 = fmaf(A[1][k], zv[k], d1);
    d2 = fmaf(A[2][k], zv[k], d2);
    d3 = fmaf(A[3][k], zv[k], d3);
  }
  d0 += __shfl_xor(d0, 1); d0 += __shfl_xor(d0, 2);
  d1 += __shfl_xor(d1, 1); d1 += __shfl_xor(d1, 2);
  d2 += __shfl_xor(d2, 1); d2 += __shfl_xor(d2, 2);
  d3 += __shfl_xor(d3, 1); d3 += __shfl_xor(d3, 2);
  if (dorel) {
    const float4 r = reinterpret_cast<const float4*>(sRel)[relrow];
    d0 += r.x; d1 += r.y; d2 += r.z; d3 += r.w;
  }
  float w0 = __expf(d0), w1 = __expf(d1), w2 = __expf(d2), w3 = __expf(d3);
  Zc[0] += w0; Zc[1] += w1; Zc[2] += w2; Zc[3] += w3;
  S[0] += zv * w0;
  S[1] += zv * w1;
  S[2] += zv * w2;
  S[3] += zv * w3;
}

// ---------------- Kernel A: per-block softmax-weighted accumulation ----------------
__global__ __launch_bounds__(BTA)
void photonic_acc(PParams p, int iter) {
  __shared__ float sZ[32];
  __shared__ float sQ[32];
  __shared__ __align__(16) float sA[128];     // a[h][c]
  __shared__ __align__(16) float sRel[256];   // relT[l][h], l<64
  __shared__ float sRed[BTA / 64][4][36];     // per-wave reduced (S[4][8] + Z[4]) per quarter

  const int tid  = threadIdx.x;
  const int b    = blockIdx.x;
  const int j    = tid & 3;        // quarter (owns columns [8j, 8j+8))
  const int quad = tid >> 2;       // 0..127
  const int wave = tid >> 6;
  const int lane = tid & 63;

  const int chunk0 = b * CHUNK;
  const int clen   = min(CHUNK, p.L - chunk0);   // 977, last block 753

  // z at start of this iteration (kernel-boundary coherence: plain load is safe)
  if (tid < 32) sZ[tid] = (iter == 0) ? p.candidate[tid] : p.ws[iter * 64 + tid];
  __syncthreads();
  compute_qar(p, tid, sZ, sQ, sA, sRel);

  // stage my quarter of a[h][*] into registers
  v8f A[4];
  #pragma unroll
  for (int h = 0; h < 4; ++h)
    A[h] = *reinterpret_cast<const v8f*>(sA + h * 32 + j * 8);

  v8f S[4];
  #pragma unroll
  for (int h = 0; h < 4; ++h) S[h] = 0.f;
  v4f Zc = 0.f;

  // stream my block's chunk (HBM on iter 0; L3-resident afterwards).
  // 8 fully-unrolled independent row-trips for ILP.
  #pragma unroll
  for (int t = 0; t < 8; ++t) {
    int r = quad + (t << 7);
    if (r < clen) {
      v8f zv = *reinterpret_cast<const v8f*>(
          p.z_past + (size_t)(chunk0 + r) * 32 + j * 8);
      trip_body(A, zv, sRel, (b == 0) && (t == 0) && (quad < 64), quad, S, Zc);
    }
  }

  // reduce across the 16 quads of each wave (lane%4 == quarter is preserved)
  #pragma unroll
  for (int m = 4; m <= 32; m <<= 1) {
    #pragma unroll
    for (int h = 0; h < 4; ++h) {
      #pragma unroll
      for (int k = 0; k < 8; ++k) S[h][k] += __shfl_xor(S[h][k], m);
      Zc[h] += __shfl_xor(Zc[h], m);
    }
  }
  if ((lane >> 2) == 0) {  // lanes 0..3: lane == quarter j
    #pragma unroll
    for (int h = 0; h < 4; ++h) {
      #pragma unroll
      for (int k = 0; k < 8; ++k) sRed[wave][lane][h * 8 + k] = S[h][k];
      sRed[wave][lane][32 + h] = Zc[h];
    }
  }
  __syncthreads();

  // per-block partials -> ws, component-major, plain coalesced stores
  float* part = p.ws + 1024;
  if (tid < 132) {
    float acc = 0.f;
    if (tid < 128) {
      int h = tid >> 5, c = tid & 31;
      int jj = c >> 3, k = c & 7;
      #pragma unroll
      for (int w2 = 0; w2 < BTA / 64; ++w2) acc += sRed[w2][jj][h * 8 + k];
    } else {
      int h = tid - 128;
      #pragma unroll
      for (int w2 = 0; w2 < BTA / 64; ++w2) acc += sRed[w2][0][32 + h];
    }
    part[tid * NBA + b] = acc;
  }
}

// ---------------- Kernel B: global reduce + serial tail (1 block) ----------------
__global__ __launch_bounds__(512)
void photonic_reduce(PParams p, int iter) {
  __shared__ float sP[132][4];
  __shared__ float sSS[128];
  __shared__ float sSZ[4];
  __shared__ float sZ[32];
  __shared__ float sOutV[32];
  __shared__ float sZn[32];

  const int tid = threadIdx.x;
  const float* part = p.ws + 1024;

  if (tid < 32) sZ[tid] = (iter == 0) ? p.candidate[tid] : p.ws[iter * 64 + tid];

  // two-level deterministic reduce: thread (cc,qq) sums a 32-float4 strip
  {
    const int cc = tid >> 2;       // component 0..127
    const int qq = tid & 3;        // quarter-strip of the 512-wide row
    const float4* pp =
        reinterpret_cast<const float4*>(part + cc * NBA) + qq * (NBA / 16);
    float acc = 0.f;
    #pragma unroll
    for (int i = 0; i < NBA / 16; ++i) {
      float4 v4 = pp[i];
      acc += (v4.x + v4.y) + (v4.z + v4.w);
    }
    sP[cc][qq] = acc;
    if (tid < 16) {                // components 128..131 (the Z row)
      const int cc2 = 128 + (tid >> 2);
      const float4* pp2 =
          reinterpret_cast<const float4*>(part + cc2 * NBA) + qq * (NBA / 16);
      float acc2 = 0.f;
      #pragma unroll
      for (int i = 0; i < NBA / 16; ++i) {
        float4 v4 = pp2[i];
        acc2 += (v4.x + v4.y) + (v4.z + v4.w);
      }
      sP[cc2][qq] = acc2;
    }
  }
  __syncthreads();
  if (tid < 132) {
    float acc = sP[tid][0] + sP[tid][1] + sP[tid][2] + sP[tid][3];
    if (tid < 128) sSS[tid] = acc; else sSZ[tid - 128] = acc;
  }
  __syncthreads();

  // out_flat[j'] = v_w[j',:] @ (S_h / Z_h) + v_b[j']   (h = j'>>3)
  if (tid < 32) {
    int h = tid >> 3;
    float acc = 0.f;
    const float* row = p.v_w + tid * 32;
    #pragma unroll
    for (int c = 0; c < 32; ++c) acc = fmaf(row[c], sSS[h * 32 + c], acc);
    sOutV[tid] = acc / sSZ[h] + p.v_b[tid];
  }
  __syncthreads();
  // mod = o_w @ out + o_b ; z += coupling*mod ; mish
  if (tid < 32) {
    float acc = p.o_b[tid];
    const float* row = p.o_w + tid * 32;
    #pragma unroll
    for (int c = 0; c < 32; ++c) acc = fmaf(row[c], sOutV[c], acc);
    float zv2 = sZ[tid] + p.coupling[0] * acc;
    sZn[tid] = mish_f(zv2);
  }
  __syncthreads();
  // layer-norm over the 16 real / 16 imag components separately
  if (tid < 32) {
    int par = tid & 1;
    float m = 0.f;
    #pragma unroll
    for (int e = 0; e < 16; ++e) m += sZn[2 * e + par];
    m *= (1.f / 16.f);
    float v = 0.f;
    #pragma unroll
    for (int e = 0; e < 16; ++e) { float dd = sZn[2 * e + par] - m; v = fmaf(dd, dd, v); }
    v *= (1.f / 16.f);
    float zn = (sZn[tid] - m) * rsqrtf(v + 1e-5f) * p.norm_scale[0];
    p.ws[(iter + 1) * 64 + tid] = zn;          // z for next iteration's kernels
    if (iter == MSTEPS - 1) p.out[tid] = zn;   // final output
  }
}

extern "C" void kernel_launch(void* const* d_in, const int* in_sizes, int n_in,
                              void* d_out, int out_size, void* d_ws, size_t ws_size,
                              hipStream_t stream) {
  PParams p;
  p.candidate  = (const float*)d_in[0];
  p.z_past     = (const float*)d_in[1];
  p.q_w = (const float*)d_in[2];  p.q_b = (const float*)d_in[3];
  p.k_w = (const float*)d_in[4];  p.k_b = (const float*)d_in[5];
  p.v_w = (const float*)d_in[6];  p.v_b = (const float*)d_in[7];
  p.o_w = (const float*)d_in[8];  p.o_b = (const float*)d_in[9];
  p.rel_bias   = (const float*)d_in[10];
  p.coupling   = (const float*)d_in[11];
  p.norm_scale = (const float*)d_in[12];
  p.out = (float*)d_out;
  p.ws  = (float*)d_ws;
  p.L   = in_sizes[1] / 32;

  // 16 plain async launches; each kernel boundary is the grid-wide sync with
  // guaranteed coherence (stream ordering). No spin barriers, no scoped atomics.
  for (int it = 0; it < MSTEPS; ++it) {
    hipLaunchKernelGGL(photonic_acc,    dim3(NBA), dim3(BTA), 0, stream, p, it);
    hipLaunchKernelGGL(photonic_reduce, dim3(1),   dim3(512), 0, stream, p, it);
  }
}

// Round 16
// 317.000 us; speedup vs baseline: 1.4384x; 1.1215x over previous
//
#include <hip/hip_runtime.h>

#define NB 256            // blocks (1 per CU — cooperative, r9-proven)
#define BT 512            // threads per block (8 waves, quad scheme, no spill at 128 VGPR)
#define MSTEPS 8
// Fixed problem shape: L = 500000.
#define CHUNK 1954        // ceil(500000 / NB) rows per block — ENTIRE chunk LDS-resident as bf16

typedef float v8f __attribute__((ext_vector_type(8)));
typedef float v4f __attribute__((ext_vector_type(4)));

// Workspace layout (r9-proven):
//  u32 region (memset to 0 at launch, 5120 B): per-iter counter block, stride 160 u32:
//    [iter*160 + g*16]  g<8 : sub-arrival counter for block-group g = b>>5
//    [iter*160 + 128]        : super-arrival counter (8 groups)
//    [iter*160 + 144]        : release flag
//  float region:
//    ws[4096 + iter*132*NB + c*NB + b] : per-iteration partial tables — FRESH each iter.
//  Coherence contract (r8-r11): publish = system-scope store + per-wave vmcnt(0)
//  drain before arrival; consume = PLAIN loads on lines never cached earlier in
//  the launch (fresh per-iter buffers only).

struct PParams {
  const float* candidate;
  const float* z_past;
  const float* q_w; const float* q_b;
  const float* k_w; const float* k_b;
  const float* v_w; const float* v_b;
  const float* o_w; const float* o_b;
  const float* rel_bias;
  const float* coupling;
  const float* norm_scale;
  float* out;
  float* ws;
  int L;
};

__device__ __forceinline__ float mish_f(float x) {
  float sp = fmaxf(x, 0.0f) + log1pf(expf(-fabsf(x)));
  return x * tanhf(sp);
}

// RTNE-pack two fp32 into one uint of 2 bf16 (lo = a, hi = b).
__device__ __forceinline__ unsigned pack_bf16(float a, float b) {
  unsigned ua = __float_as_uint(a), ub = __float_as_uint(b);
  ua = (ua + 0x7FFFu + ((ua >> 16) & 1u)) >> 16;
  ub = (ub + 0x7FFFu + ((ub >> 16) & 1u)) & 0xFFFF0000u;
  return ua | ub;
}

// Recompute q projection, folded score vectors a_h (pre-scaled by inv_sqrt_d=0.5),
// and the l<64 relative-bias delta table, from the current state sZ.
// Must be called by ALL threads of the block (contains barriers).
__device__ void compute_qar(const PParams& p, int tid,
                            float* sZ, float* sQ, float* sA, float* sRel) {
  if (tid < 32) {
    float acc = p.q_b[tid];
    const float* row = p.q_w + tid * 32;
    #pragma unroll
    for (int c = 0; c < 32; ++c) acc = fmaf(row[c], sZ[c], acc);
    sQ[tid] = acc;
  }
  __syncthreads();
  if (tid < 128) {
    int h = tid >> 5, c = tid & 31;
    float acc = 0.f;
    #pragma unroll
    for (int jj = 0; jj < 8; ++jj)
      acc = fmaf(sQ[8 * h + jj], p.k_w[(8 * h + jj) * 32 + c], acc);
    sA[tid] = 0.5f * acc;               // fold inv_sqrt_d
  }
  if (tid >= 256) {
    // rel-bias delta vs the saturated idx=128 entry (constant part cancels in softmax)
    int t = tid - 256;
    int l = t >> 2, h = t & 3;
    float acc = 0.f;
    #pragma unroll
    for (int jj = 0; jj < 8; ++jj) {
      int jidx = 8 * h + jj;
      acc = fmaf(sQ[jidx],
                 p.rel_bias[(l + 64) * 32 + jidx] - p.rel_bias[128 * 32 + jidx],
                 acc);
    }
    sRel[t] = 0.5f * acc;
  }
  __syncthreads();
}

// One l-row contribution (quad scheme: 4 lanes own one 32-float row, 8 floats each).
__device__ __forceinline__ void trip_body(const v8f (&A)[4], v8f zv,
                                          const float* sRel, bool dorel, int relrow,
                                          v8f (&S)[4], v4f& Zc) {
  float d0 = 0.f, d1 = 0.f, d2 = 0.f, d3 = 0.f;
  #pragma unroll
  for (int k = 0; k < 8; ++k) {
    d0 = fmaf(A[0][k], zv[k], d0);
    d1 = fmaf(A[1][k], zv[k], d1);
    d2 = fmaf(A[2][k], zv[k], d2);
    d3 = fmaf(A[3][k], zv[k], d3);
  }
  d0 += __shfl_xor(d0, 1); d0 += __shfl_xor(d0, 2);
  d1 += __shfl_xor(d1, 1); d1 += __shfl_xor(d1, 2);
  d2 += __shfl_xor(d2, 1); d2 += __shfl_xor(d2, 2);
  d3 += __shfl_xor(d3, 1); d3 += __shfl_xor(d3, 2);
  if (dorel) {
    const float4 r = reinterpret_cast<const float4*>(sRel)[relrow];
    d0 += r.x; d1 += r.y; d2 += r.z; d3 += r.w;
  }
  float w0 = __expf(d0), w1 = __expf(d1), w2 = __expf(d2), w3 = __expf(d3);
  Zc[0] += w0; Zc[1] += w1; Zc[2] += w2; Zc[3] += w3;
  S[0] += zv * w0;
  S[1] += zv * w1;
  S[2] += zv * w2;
  S[3] += zv * w3;
}

__global__ __launch_bounds__(BT)
void photonic_kernel(PParams p) {
  __shared__ float sZ[32];
  __shared__ float sQ[32];
  __shared__ float sOutV[32];
  __shared__ float sZn[32];
  __shared__ __align__(16) float sA[128];     // a[h][c]
  __shared__ __align__(16) float sRel[256];   // relT[l][h], l<64
  __shared__ float sRed[BT / 64][4][36];      // per-wave reduced (S[4][8] + Z[4]) per quarter
  __shared__ float sP[132][4];                // level-2 strip sums
  __shared__ float sSS[128];                  // global-reduced S[h][c]
  __shared__ float sSZ[4];                    // global-reduced Z[h]
  __shared__ __align__(16) unsigned sZp[CHUNK * 16];  // bf16-packed z rows (64 B/row, 125 KB)

  const int tid  = threadIdx.x;
  const int b    = blockIdx.x;
  const int j    = tid & 3;        // quarter (owns columns [8j, 8j+8))
  const int quad = tid >> 2;       // 0..127
  const int wave = tid >> 6;
  const int lane = tid & 63;

  const int chunk0 = b * CHUNK;
  const int clen   = min(CHUNK, p.L - chunk0);   // 1954, last block 1730

  // init state z = candidate (real-interleaved flat 32)
  if (tid < 32) sZ[tid] = p.candidate[tid];
  __syncthreads();
  compute_qar(p, tid, sZ, sQ, sA, sRel);

  for (int iter = 0; iter < MSTEPS; ++iter) {
    // stage my quarter of a[h][*] into registers
    v8f A[4];
    #pragma unroll
    for (int h = 0; h < 4; ++h)
      A[h] = *reinterpret_cast<const v8f*>(sA + h * 32 + j * 8);

    v8f S[4];
    #pragma unroll
    for (int h = 0; h < 4; ++h) S[h] = 0.f;
    v4f Zc = 0.f;

    if (iter == 0) {
      // ---- first pass: stream fp32 rows from HBM, compute with exact values,
      //      and stash the whole chunk as bf16 in LDS ----
      #pragma unroll
      for (int t = 0; t < 16; ++t) {
        int li = quad + (t << 7);
        if (li < clen) {
          v8f zv = *reinterpret_cast<const v8f*>(
              p.z_past + (size_t)(chunk0 + li) * 32 + j * 8);
          uint4 pk;
          pk.x = pack_bf16(zv[0], zv[1]);
          pk.y = pack_bf16(zv[2], zv[3]);
          pk.z = pack_bf16(zv[4], zv[5]);
          pk.w = pack_bf16(zv[6], zv[7]);
          *reinterpret_cast<uint4*>(sZp + li * 16 + j * 4) = pk;
          trip_body(A, zv, sRel, (b == 0) && (t == 0) && (quad < 64), quad, S, Zc);
        }
      }
    } else {
      // ---- steady state: ZERO global traffic — entire chunk from LDS (bf16) ----
      #pragma unroll
      for (int t = 0; t < 16; ++t) {
        int li = quad + (t << 7);
        if (li < clen) {
          uint4 pk = *reinterpret_cast<const uint4*>(sZp + li * 16 + j * 4);
          v8f zv;
          zv[0] = __uint_as_float(pk.x << 16);
          zv[1] = __uint_as_float(pk.x & 0xFFFF0000u);
          zv[2] = __uint_as_float(pk.y << 16);
          zv[3] = __uint_as_float(pk.y & 0xFFFF0000u);
          zv[4] = __uint_as_float(pk.z << 16);
          zv[5] = __uint_as_float(pk.z & 0xFFFF0000u);
          zv[6] = __uint_as_float(pk.w << 16);
          zv[7] = __uint_as_float(pk.w & 0xFFFF0000u);
          trip_body(A, zv, sRel, (b == 0) && (t == 0) && (quad < 64), quad, S, Zc);
        }
      }
    }

    // reduce across the 16 quads of each wave (lane%4 == quarter is preserved)
    #pragma unroll
    for (int m = 4; m <= 32; m <<= 1) {
      #pragma unroll
      for (int h = 0; h < 4; ++h) {
        #pragma unroll
        for (int k = 0; k < 8; ++k) S[h][k] += __shfl_xor(S[h][k], m);
        Zc[h] += __shfl_xor(Zc[h], m);
      }
    }
    if ((lane >> 2) == 0) {  // lanes 0..3: lane == quarter j
      #pragma unroll
      for (int h = 0; h < 4; ++h) {
        #pragma unroll
        for (int k = 0; k < 8; ++k) sRed[wave][lane][h * 8 + k] = S[h][k];
        sRed[wave][lane][32 + h] = Zc[h];
      }
    }
    __syncthreads();

    // ---- publish per-block partials, system-scope (performed at IF);
    //      FRESH buffer per iteration (coherence contract) ----
    float* pb = p.ws + 4096 + iter * (132 * NB);
    if (tid < 132) {
      float acc = 0.f;
      if (tid < 128) {
        int h = tid >> 5, c = tid & 31;
        int jj = c >> 3, k = c & 7;
        #pragma unroll
        for (int w2 = 0; w2 < BT / 64; ++w2) acc += sRed[w2][jj][h * 8 + k];
      } else {
        int h = tid - 128;
        #pragma unroll
        for (int w2 = 0; w2 < BT / 64; ++w2) acc += sRed[w2][0][32 + h];
      }
      __hip_atomic_store(&pb[tid * NB + b], acc, __ATOMIC_RELAXED,
                         __HIP_MEMORY_SCOPE_SYSTEM);
    }
    // every wave drains its own stores; the barrier then guarantees all 132
    // stores of this block are performed before tid 0 arrives.
    asm volatile("s_waitcnt vmcnt(0)" ::: "memory");
    __syncthreads();

    // ---- two-level arrival + flag barrier (r9-proven), system scope ----
    {
      unsigned* cb = reinterpret_cast<unsigned*>(p.ws) + iter * 160;
      if (tid == 0) {
        unsigned* sub = cb + ((b >> 5) << 4);   // 8 counters on separate lines
        if (__hip_atomic_fetch_add(sub, 1u, __ATOMIC_RELAXED,
                                   __HIP_MEMORY_SCOPE_SYSTEM) == 31u) {
          if (__hip_atomic_fetch_add(cb + 128, 1u, __ATOMIC_RELAXED,
                                     __HIP_MEMORY_SCOPE_SYSTEM) == 7u) {
            __hip_atomic_store(cb + 144, 1u, __ATOMIC_RELAXED,
                               __HIP_MEMORY_SCOPE_SYSTEM);
          }
        }
        while (__hip_atomic_load(cb + 144, __ATOMIC_RELAXED,
                                 __HIP_MEMORY_SCOPE_SYSTEM) == 0u)
          __builtin_amdgcn_s_sleep(1);
      }
      __syncthreads();
    }

    // ---- level-2 reduce with plain coalesced float4 loads (fresh per-iter
    //      buffer: no cache can hold a stale copy). ALL 512 threads. ----
    {
      const int cc = tid >> 2;       // component 0..127
      const int qq = tid & 3;        // quarter-strip of the 256-wide row
      const float4* pp =
          reinterpret_cast<const float4*>(pb + cc * NB) + qq * (NB / 16);
      float acc = 0.f;
      #pragma unroll
      for (int i = 0; i < NB / 16; ++i) {
        float4 v4 = pp[i];
        acc += (v4.x + v4.y) + (v4.z + v4.w);
      }
      sP[cc][qq] = acc;
      if (tid < 16) {                // components 128..131 (the Z row)
        const int cc2 = 128 + (tid >> 2);
        const float4* pp2 =
            reinterpret_cast<const float4*>(pb + cc2 * NB) + qq * (NB / 16);
        float acc2 = 0.f;
        #pragma unroll
        for (int i = 0; i < NB / 16; ++i) {
          float4 v4 = pp2[i];
          acc2 += (v4.x + v4.y) + (v4.z + v4.w);
        }
        sP[cc2][qq] = acc2;
      }
    }
    __syncthreads();
    if (tid < 132) {
      float acc = sP[tid][0] + sP[tid][1] + sP[tid][2] + sP[tid][3];
      if (tid < 128) sSS[tid] = acc; else sSZ[tid - 128] = acc;
    }
    __syncthreads();

    // out_flat[j'] = v_w[j',:] @ (S_h / Z_h) + v_b[j']   (h = j'>>3)
    if (tid < 32) {
      int h = tid >> 3;
      float acc = 0.f;
      const float* row = p.v_w + tid * 32;
      #pragma unroll
      for (int c = 0; c < 32; ++c) acc = fmaf(row[c], sSS[h * 32 + c], acc);
      sOutV[tid] = acc / sSZ[h] + p.v_b[tid];
    }
    __syncthreads();
    // mod = o_w @ out + o_b ; z += coupling*mod ; mish
    if (tid < 32) {
      float acc = p.o_b[tid];
      const float* row = p.o_w + tid * 32;
      #pragma unroll
      for (int c = 0; c < 32; ++c) acc = fmaf(row[c], sOutV[c], acc);
      float zv2 = sZ[tid] + p.coupling[0] * acc;
      sZn[tid] = mish_f(zv2);
    }
    __syncthreads();
    // layer-norm over the 16 real / 16 imag components separately
    if (tid < 32) {
      int par = tid & 1;
      float m = 0.f;
      #pragma unroll
      for (int e = 0; e < 16; ++e) m += sZn[2 * e + par];
      m *= (1.f / 16.f);
      float v = 0.f;
      #pragma unroll
      for (int e = 0; e < 16; ++e) { float dd = sZn[2 * e + par] - m; v = fmaf(dd, dd, v); }
      v *= (1.f / 16.f);
      sZ[tid] = (sZn[tid] - m) * rsqrtf(v + 1e-5f) * p.norm_scale[0];
    }
    __syncthreads();

    if (iter != MSTEPS - 1) {
      compute_qar(p, tid, sZ, sQ, sA, sRel);
    } else {
      if (b == 0 && tid < 32) p.out[tid] = sZ[tid];
    }
  }
}

extern "C" void kernel_launch(void* const* d_in, const int* in_sizes, int n_in,
                              void* d_out, int out_size, void* d_ws, size_t ws_size,
                              hipStream_t stream) {
  PParams p;
  p.candidate  = (const float*)d_in[0];
  p.z_past     = (const float*)d_in[1];
  p.q_w = (const float*)d_in[2];  p.q_b = (const float*)d_in[3];
  p.k_w = (const float*)d_in[4];  p.k_b = (const float*)d_in[5];
  p.v_w = (const float*)d_in[6];  p.v_b = (const float*)d_in[7];
  p.o_w = (const float*)d_in[8];  p.o_b = (const float*)d_in[9];
  p.rel_bias   = (const float*)d_in[10];
  p.coupling   = (const float*)d_in[11];
  p.norm_scale = (const float*)d_in[12];
  p.out = (float*)d_out;
  p.ws  = (float*)d_ws;
  p.L   = in_sizes[1] / 32;

  // zero the per-iteration barrier counters (8 iters x 160 u32 = 5120 B);
  // captured as a graph node -> re-zeroed every replay. Partial tables are
  // fully written before being read each iteration.
  hipMemsetAsync(d_ws, 0, 5120, stream);

  void* args[] = { &p };
  hipLaunchCooperativeKernel((const void*)photonic_kernel,
                             dim3(NB), dim3(BT), args, 0, stream);
}

// Round 17
// 305.520 us; speedup vs baseline: 1.4924x; 1.0376x over previous
//
#include <hip/hip_runtime.h>

#define NB 256            // blocks (1 per CU — cooperative, proven)
#define BT 512            // threads per block (8 waves, quad scheme, no spill at 128 VGPR)
#define MSTEPS 8
// Fixed problem shape: L = 500000.
#define CHUNK 1954        // ceil(500000 / NB) rows per block
#define LDSR 1120         // rows resident in LDS (dense 128 B rows, 143 KB)

typedef float v8f __attribute__((ext_vector_type(8)));
typedef float v4f __attribute__((ext_vector_type(4)));

// Workspace layout:
//  u32 region (memset to 0 at launch, 131584 B):
//    uws[iter*4096 + b*16] : per-block arrival flag (64 B-spaced, fresh per iter)
//    uws[32768 + iter*16]  : release flag (fresh line per iter)
//  float region (offset 40960 floats):
//    ws[40960 + iter*132*NB + c*NB + b] : per-iteration partial tables — FRESH each iter.
//  Coherence contract (r8-r11 evidence): publish = system-scope store + per-wave
//  vmcnt(0) drain before the flag; consume = PLAIN loads on lines never cached
//  earlier in the launch (fresh per-iter buffers); spins use system-scope loads
//  (bypass caches by scope). No contended RMW anywhere (r17 change: the r9
//  two-level counter serialized 32 system RMWs per line — replaced by per-block
//  flags + parallel poll by block 0).

struct PParams {
  const float* candidate;
  const float* z_past;
  const float* q_w; const float* q_b;
  const float* k_w; const float* k_b;
  const float* v_w; const float* v_b;
  const float* o_w; const float* o_b;
  const float* rel_bias;
  const float* coupling;
  const float* norm_scale;
  float* out;
  float* ws;
  int L;
};

__device__ __forceinline__ float mish_f(float x) {
  float sp = fmaxf(x, 0.0f) + log1pf(expf(-fabsf(x)));
  return x * tanhf(sp);
}

// Recompute q projection, folded score vectors a_h (pre-scaled by inv_sqrt_d=0.5),
// and the l<64 relative-bias delta table, from the current state sZ.
// Must be called by ALL threads of the block (contains barriers).
__device__ void compute_qar(const PParams& p, int tid,
                            float* sZ, float* sQ, float* sA, float* sRel) {
  if (tid < 32) {
    float acc = p.q_b[tid];
    const float* row = p.q_w + tid * 32;
    #pragma unroll
    for (int c = 0; c < 32; ++c) acc = fmaf(row[c], sZ[c], acc);
    sQ[tid] = acc;
  }
  __syncthreads();
  if (tid < 128) {
    int h = tid >> 5, c = tid & 31;
    float acc = 0.f;
    #pragma unroll
    for (int jj = 0; jj < 8; ++jj)
      acc = fmaf(sQ[8 * h + jj], p.k_w[(8 * h + jj) * 32 + c], acc);
    sA[tid] = 0.5f * acc;               // fold inv_sqrt_d
  }
  if (tid >= 256) {
    // rel-bias delta vs the saturated idx=128 entry (constant part cancels in softmax)
    int t = tid - 256;
    int l = t >> 2, h = t & 3;
    float acc = 0.f;
    #pragma unroll
    for (int jj = 0; jj < 8; ++jj) {
      int jidx = 8 * h + jj;
      acc = fmaf(sQ[jidx],
                 p.rel_bias[(l + 64) * 32 + jidx] - p.rel_bias[128 * 32 + jidx],
                 acc);
    }
    sRel[t] = 0.5f * acc;
  }
  __syncthreads();
}

// One l-row contribution (quad scheme: 4 lanes own one 32-float row, 8 floats each).
__device__ __forceinline__ void trip_body(const v8f (&A)[4], v8f zv,
                                          const float* sRel, bool dorel, int relrow,
                                          v8f (&S)[4], v4f& Zc) {
  float d0 = 0.f, d1 = 0.f, d2 = 0.f, d3 = 0.f;
  #pragma unroll
  for (int k = 0; k < 8; ++k) {
    d0 = fmaf(A[0][k], zv[k], d0);
    d1 = fmaf(A[1][k], zv[k], d1);
    d2 = fmaf(A[2][k], zv[k], d2);
    d3 = fmaf(A[3][k], zv[k], d3);
  }
  d0 += __shfl_xor(d0, 1); d0 += __shfl_xor(d0, 2);
  d1 += __shfl_xor(d1, 1); d1 += __shfl_xor(d1, 2);
  d2 += __shfl_xor(d2, 1); d2 += __shfl_xor(d2, 2);
  d3 += __shfl_xor(d3, 1); d3 += __shfl_xor(d3, 2);
  if (dorel) {
    const float4 r = reinterpret_cast<const float4*>(sRel)[relrow];
    d0 += r.x; d1 += r.y; d2 += r.z; d3 += r.w;
  }
  float w0 = __expf(d0), w1 = __expf(d1), w2 = __expf(d2), w3 = __expf(d3);
  Zc[0] += w0; Zc[1] += w1; Zc[2] += w2; Zc[3] += w3;
  S[0] += zv * w0;
  S[1] += zv * w1;
  S[2] += zv * w2;
  S[3] += zv * w3;
}

__global__ __launch_bounds__(BT)
void photonic_kernel(PParams p) {
  __shared__ float sZ[32];
  __shared__ float sQ[32];
  __shared__ float sOutV[32];
  __shared__ float sZn[32];
  __shared__ __align__(16) float sA[128];     // a[h][c]
  __shared__ __align__(16) float sRel[256];   // relT[l][h], l<64
  __shared__ float sRed[BT / 64][4][36];      // per-wave reduced (S[4][8] + Z[4]) per quarter
  __shared__ float sP[132][4];                // level-2 strip sums
  __shared__ float sSS[128];                  // global-reduced S[h][c]
  __shared__ float sSZ[4];                    // global-reduced Z[h]
  __shared__ __align__(16) float sZp[LDSR * 32];  // LDS-resident z rows (dense, XOR-swizzled)

  const int tid  = threadIdx.x;
  const int b    = blockIdx.x;
  const int j    = tid & 3;        // quarter (owns columns [8j, 8j+8))
  const int quad = tid >> 2;       // 0..127
  const int wave = tid >> 6;
  const int lane = tid & 63;

  const int chunk0 = b * CHUNK;
  const int clen   = min(CHUNK, p.L - chunk0);   // 1954, last block 1730
  const int ldsl   = min(clen, (int)LDSR);       // 1120 everywhere

  unsigned* uws = reinterpret_cast<unsigned*>(p.ws);

  // init state z = candidate (real-interleaved flat 32)
  if (tid < 32) sZ[tid] = p.candidate[tid];
  __syncthreads();
  compute_qar(p, tid, sZ, sQ, sA, sRel);

  for (int iter = 0; iter < MSTEPS; ++iter) {
    // stage my quarter of a[h][*] into registers
    v8f A[4];
    #pragma unroll
    for (int h = 0; h < 4; ++h)
      A[h] = *reinterpret_cast<const v8f*>(sA + h * 32 + j * 8);

    v8f S[4];
    #pragma unroll
    for (int h = 0; h < 4; ++h) S[h] = 0.f;
    v4f Zc = 0.f;

    if (iter == 0) {
      // ---- first pass: LDS rows from HBM, stashed XOR-swizzled; rest streamed ----
      #pragma unroll
      for (int t = 0; t < 9; ++t) {
        int li = quad + (t << 7);
        if (li < ldsl) {
          v8f zv = *reinterpret_cast<const v8f*>(
              p.z_past + (size_t)(chunk0 + li) * 32 + j * 8);
          int jx = j ^ (li & 3);               // bank swizzle (bijective in j)
          float* dst = sZp + li * 32 + jx * 8;
          *reinterpret_cast<v4f*>(dst)     = __builtin_shufflevector(zv, zv, 0, 1, 2, 3);
          *reinterpret_cast<v4f*>(dst + 4) = __builtin_shufflevector(zv, zv, 4, 5, 6, 7);
          trip_body(A, zv, sRel, (b == 0) && (t == 0) && (quad < 64), quad, S, Zc);
        }
      }
    } else {
      // ---- steady state: LDS-resident rows (same swizzle on the read side) ----
      #pragma unroll
      for (int t = 0; t < 9; ++t) {
        int li = quad + (t << 7);
        if (li < ldsl) {
          int jx = j ^ (li & 3);
          const float* src = sZp + li * 32 + jx * 8;
          v4f a4 = *reinterpret_cast<const v4f*>(src);
          v4f b4 = *reinterpret_cast<const v4f*>(src + 4);
          v8f zv = __builtin_shufflevector(a4, b4, 0, 1, 2, 3, 4, 5, 6, 7);
          trip_body(A, zv, sRel, (b == 0) && (t == 0) && (quad < 64), quad, S, Zc);
        }
      }
    }
    // ---- streamed remainder (27 MB grid-wide; L2/L3-resident after pass 1 —
    //      overlaps the LDS loop through the global-memory pipe) ----
    for (int r = LDSR + quad; r < clen; r += 128) {
      v8f zv = *reinterpret_cast<const v8f*>(
          p.z_past + (size_t)(chunk0 + r) * 32 + j * 8);
      trip_body(A, zv, sRel, false, 0, S, Zc);
    }

    // reduce across the 16 quads of each wave (lane%4 == quarter is preserved)
    #pragma unroll
    for (int m = 4; m <= 32; m <<= 1) {
      #pragma unroll
      for (int h = 0; h < 4; ++h) {
        #pragma unroll
        for (int k = 0; k < 8; ++k) S[h][k] += __shfl_xor(S[h][k], m);
        Zc[h] += __shfl_xor(Zc[h], m);
      }
    }
    if ((lane >> 2) == 0) {  // lanes 0..3: lane == quarter j
      #pragma unroll
      for (int h = 0; h < 4; ++h) {
        #pragma unroll
        for (int k = 0; k < 8; ++k) sRed[wave][lane][h * 8 + k] = S[h][k];
        sRed[wave][lane][32 + h] = Zc[h];
      }
    }
    __syncthreads();

    // ---- publish per-block partials, system-scope (performed at IF);
    //      FRESH buffer per iteration (coherence contract) ----
    float* pb = p.ws + 40960 + iter * (132 * NB);
    if (tid < 132) {
      float acc = 0.f;
      if (tid < 128) {
        int h = tid >> 5, c = tid & 31;
        int jj = c >> 3, k = c & 7;
        #pragma unroll
        for (int w2 = 0; w2 < BT / 64; ++w2) acc += sRed[w2][jj][h * 8 + k];
      } else {
        int h = tid - 128;
        #pragma unroll
        for (int w2 = 0; w2 < BT / 64; ++w2) acc += sRed[w2][0][32 + h];
      }
      __hip_atomic_store(&pb[tid * NB + b], acc, __ATOMIC_RELAXED,
                         __HIP_MEMORY_SCOPE_SYSTEM);
    }
    // every wave drains its own stores; the barrier then guarantees all 132
    // stores of this block are performed before the arrival flag goes up.
    asm volatile("s_waitcnt vmcnt(0)" ::: "memory");
    __syncthreads();

    // ---- contention-free flag barrier ----
    if (tid == 0)
      __hip_atomic_store(&uws[iter * 4096 + b * 16], 1u, __ATOMIC_RELAXED,
                         __HIP_MEMORY_SCOPE_SYSTEM);
    if (b == 0) {
      // block 0: poll all 256 arrival flags in parallel (one latency burst)
      if (tid < NB) {
        while (__hip_atomic_load(&uws[iter * 4096 + tid * 16], __ATOMIC_RELAXED,
                                 __HIP_MEMORY_SCOPE_SYSTEM) == 0u) {}
      }
      __syncthreads();
      if (tid == 0)
        __hip_atomic_store(&uws[32768 + iter * 16], 1u, __ATOMIC_RELAXED,
                           __HIP_MEMORY_SCOPE_SYSTEM);
    } else {
      if (tid == 0) {
        while (__hip_atomic_load(&uws[32768 + iter * 16], __ATOMIC_RELAXED,
                                 __HIP_MEMORY_SCOPE_SYSTEM) == 0u)
          __builtin_amdgcn_s_sleep(1);
      }
      __syncthreads();
    }

    // ---- level-2 reduce with plain coalesced float4 loads (fresh per-iter
    //      buffer: no cache can hold a stale copy). ALL 512 threads. ----
    {
      const int cc = tid >> 2;       // component 0..127
      const int qq = tid & 3;        // quarter-strip of the 256-wide row
      const float4* pp =
          reinterpret_cast<const float4*>(pb + cc * NB) + qq * (NB / 16);
      float acc = 0.f;
      #pragma unroll
      for (int i = 0; i < NB / 16; ++i) {
        float4 v4 = pp[i];
        acc += (v4.x + v4.y) + (v4.z + v4.w);
      }
      sP[cc][qq] = acc;
      if (tid < 16) {                // components 128..131 (the Z row)
        const int cc2 = 128 + (tid >> 2);
        const float4* pp2 =
            reinterpret_cast<const float4*>(pb + cc2 * NB) + qq * (NB / 16);
        float acc2 = 0.f;
        #pragma unroll
        for (int i = 0; i < NB / 16; ++i) {
          float4 v4 = pp2[i];
          acc2 += (v4.x + v4.y) + (v4.z + v4.w);
        }
        sP[cc2][qq] = acc2;
      }
    }
    __syncthreads();
    if (tid < 132) {
      float acc = sP[tid][0] + sP[tid][1] + sP[tid][2] + sP[tid][3];
      if (tid < 128) sSS[tid] = acc; else sSZ[tid - 128] = acc;
    }
    __syncthreads();

    // out_flat[j'] = v_w[j',:] @ (S_h / Z_h) + v_b[j']   (h = j'>>3)
    if (tid < 32) {
      int h = tid >> 3;
      float acc = 0.f;
      const float* row = p.v_w + tid * 32;
      #pragma unroll
      for (int c = 0; c < 32; ++c) acc = fmaf(row[c], sSS[h * 32 + c], acc);
      sOutV[tid] = acc / sSZ[h] + p.v_b[tid];
    }
    __syncthreads();
    // mod = o_w @ out + o_b ; z += coupling*mod ; mish
    if (tid < 32) {
      float acc = p.o_b[tid];
      const float* row = p.o_w + tid * 32;
      #pragma unroll
      for (int c = 0; c < 32; ++c) acc = fmaf(row[c], sOutV[c], acc);
      float zv2 = sZ[tid] + p.coupling[0] * acc;
      sZn[tid] = mish_f(zv2);
    }
    __syncthreads();
    // layer-norm over the 16 real / 16 imag components separately
    if (tid < 32) {
      int par = tid & 1;
      float m = 0.f;
      #pragma unroll
      for (int e = 0; e < 16; ++e) m += sZn[2 * e + par];
      m *= (1.f / 16.f);
      float v = 0.f;
      #pragma unroll
      for (int e = 0; e < 16; ++e) { float dd = sZn[2 * e + par] - m; v = fmaf(dd, dd, v); }
      v *= (1.f / 16.f);
      sZ[tid] = (sZn[tid] - m) * rsqrtf(v + 1e-5f) * p.norm_scale[0];
    }
    __syncthreads();

    if (iter != MSTEPS - 1) {
      compute_qar(p, tid, sZ, sQ, sA, sRel);
    } else {
      if (b == 0 && tid < 32) p.out[tid] = sZ[tid];
    }
  }
}

extern "C" void kernel_launch(void* const* d_in, const int* in_sizes, int n_in,
                              void* d_out, int out_size, void* d_ws, size_t ws_size,
                              hipStream_t stream) {
  PParams p;
  p.candidate  = (const float*)d_in[0];
  p.z_past     = (const float*)d_in[1];
  p.q_w = (const float*)d_in[2];  p.q_b = (const float*)d_in[3];
  p.k_w = (const float*)d_in[4];  p.k_b = (const float*)d_in[5];
  p.v_w = (const float*)d_in[6];  p.v_b = (const float*)d_in[7];
  p.o_w = (const float*)d_in[8];  p.o_b = (const float*)d_in[9];
  p.rel_bias   = (const float*)d_in[10];
  p.coupling   = (const float*)d_in[11];
  p.norm_scale = (const float*)d_in[12];
  p.out = (float*)d_out;
  p.ws  = (float*)d_ws;
  p.L   = in_sizes[1] / 32;

  // zero arrival + release flags (8 iters x 4096 u32 + release region = 131584 B);
  // captured as a graph node -> re-zeroed every replay. Partial tables are
  // fully written before being read each iteration.
  hipMemsetAsync(d_ws, 0, 131584, stream);

  void* args[] = { &p };
  hipLaunchCooperativeKernel((const void*)photonic_kernel,
                             dim3(NB), dim3(BT), args, 0, stream);
}